// Round 21
// baseline (324.725 us; speedup 1.0000x reference)
//
#include <hip/hip_runtime.h>

// VanillaRNN: B=4096, T=1024, I=3, H=32, O=2
// out[b,t,j] = h_t[j];  h_t = tanh(x_t @ W_ih^T + b_ih + b_hh + h_{t-1} @ W_hh^T)
// h_n[b,o] = h_T @ W_fc^T + b_fc
//
// R19: MFMA. One wave (64 thr) per block handles 16 batches; 256 blocks.
//   D(16j x 16batch) = A(W-half 16x32) @ B(H 32x16) + C(xp)   [f16 in, f32 acc]
//   via 2x v_mfma_f32_16x16x32_f16 per step (j halves). h passes steps
//   through a 16x40-padded f16 LDS tile: each lane re-reads its B-fragment
//   (1 ds_read_b128) and writes back 2x8B after tanh. Single wave -> no
//   barriers; DS queue is in-order.
// Layouts: C/D col=lane&15(batch), row=(lane>>4)*4+r (j) [guide-verified].
//   A/B assumed standard: lane&15 = A-row/B-col, k = (lane>>4)*8+e.
// Removes the fdot2 floor (32/step -> 2 mfma) and ALL explicit exchange.

typedef float     f4  __attribute__((ext_vector_type(4)));
typedef _Float16  h8  __attribute__((ext_vector_type(8)));

#define RNN_B 4096
#define RNN_T 1024
#define SCALE 2.8853900817779268f   // 2*log2(e)

__global__ __launch_bounds__(64, 1) void vanilla_rnn_kernel(
    const float* __restrict__ x,     // [B,T,3]
    const float* __restrict__ W_ih,  // [32,3]
    const float* __restrict__ b_ih,  // [32]
    const float* __restrict__ W_hh,  // [32,32]
    const float* __restrict__ b_hh,  // [32]
    const float* __restrict__ W_fc,  // [2,32]
    const float* __restrict__ b_fc,  // [2]
    float* __restrict__ out,         // [B,T,32]
    float* __restrict__ hn_out)      // [B,2]
{
    const int lane = threadIdx.x;      // one wave per block
    const int bb   = lane & 15;        // batch within wave (B/D col, A row)
    const int gq   = lane >> 4;        // 0..3
    const int b    = blockIdx.x * 16 + bb;
    const int j0   = 4 * gq;           // D rows j0..j0+3 (+16 for half 2)

    __shared__ _Float16 hbuf[16][40];  // h state; 80B rows for bank spread

    // zero h (single wave; DS in-order)
    {
        _Float16* hb = &hbuf[0][0];
        for (int i = lane; i < 16 * 40; i += 64) hb[i] = (_Float16)0.0f;
    }

    // A fragments (constant): A[m][k], m=lane&15 (j row), k=8*gq+e. Scaled.
    h8 A1, A2;
#pragma unroll
    for (int e = 0; e < 8; ++e) {
        const int k = 8 * gq + e;
        A1[e] = (_Float16)(W_hh[bb * 32 + k]        * SCALE);
        A2[e] = (_Float16)(W_hh[(bb + 16) * 32 + k] * SCALE);
    }

    // C coefficients for lane's 8 output rows: [half][r][wi0,wi1,wi2,bias]
    float cw[2][4][4];
#pragma unroll
    for (int hf = 0; hf < 2; ++hf)
#pragma unroll
        for (int r = 0; r < 4; ++r) {
            const int j = j0 + r + 16 * hf;
            cw[hf][r][0] = W_ih[j * 3 + 0] * SCALE;
            cw[hf][r][1] = W_ih[j * 3 + 1] * SCALE;
            cw[hf][r][2] = W_ih[j * 3 + 2] * SCALE;
            cw[hf][r][3] = (b_ih[j] + b_hh[j]) * SCALE;
        }

    const float4* xb4 = reinterpret_cast<const float4*>(x + (size_t)b * RNN_T * 3);
    float*        ob  = out + (size_t)b * RNN_T * 32;

    float4 cx0 = xb4[0], cx1 = xb4[1], cx2 = xb4[2];   // block 0's x (4 steps)

    for (int k = 0; k < RNN_T / 4; ++k) {
        const int kn = (k + 1 < RNN_T / 4) ? k + 1 : k;
        const float4 nx0 = xb4[3 * kn + 0];
        const float4 nx1 = xb4[3 * kn + 1];
        const float4 nx2 = xb4[3 * kn + 2];

        const float xv[12] = {cx0.x, cx0.y, cx0.z, cx0.w,
                              cx1.x, cx1.y, cx1.z, cx1.w,
                              cx2.x, cx2.y, cx2.z, cx2.w};

#pragma unroll
        for (int d = 0; d < 4; ++d) {
            // B fragment: H[k=8*gq+e][batch=bb] from hbuf[bb][8*gq..+7]
            const h8 bf = *reinterpret_cast<const h8*>(&hbuf[bb][8 * gq]);

            // C = xp for this step (lane's 8 rows)
            f4 c1, c2;
#pragma unroll
            for (int r = 0; r < 4; ++r) {
                c1[r] = fmaf(cw[0][r][0], xv[3 * d + 0],
                        fmaf(cw[0][r][1], xv[3 * d + 1],
                        fmaf(cw[0][r][2], xv[3 * d + 2], cw[0][r][3])));
                c2[r] = fmaf(cw[1][r][0], xv[3 * d + 0],
                        fmaf(cw[1][r][1], xv[3 * d + 1],
                        fmaf(cw[1][r][2], xv[3 * d + 2], cw[1][r][3])));
            }

            const f4 d1 = __builtin_amdgcn_mfma_f32_16x16x32_f16(A1, bf, c1, 0, 0, 0);
            const f4 d2 = __builtin_amdgcn_mfma_f32_16x16x32_f16(A2, bf, c2, 0, 0, 0);

            // tanh(z) = 1 - 2/(exp2(2*log2e*z)+1); inf-safe
            f4 t1, t2;
#pragma unroll
            for (int r = 0; r < 4; ++r) {
                t1[r] = fmaf(-2.0f, __builtin_amdgcn_rcpf(exp2f(d1[r]) + 1.0f), 1.0f);
                t2[r] = fmaf(-2.0f, __builtin_amdgcn_rcpf(exp2f(d2[r]) + 1.0f), 1.0f);
            }

            const int t = k * 4 + d;
            __builtin_nontemporal_store(t1, reinterpret_cast<f4*>(ob + (size_t)t * 32 + j0));
            __builtin_nontemporal_store(t2, reinterpret_cast<f4*>(ob + (size_t)t * 32 + j0 + 16));

            // write h back (f16): rows j0..j0+3 and j0+16..+19 of own batch
            uint2 w1, w2;
            w1.x = __builtin_bit_cast(unsigned, __builtin_amdgcn_cvt_pkrtz(t1[0], t1[1]));
            w1.y = __builtin_bit_cast(unsigned, __builtin_amdgcn_cvt_pkrtz(t1[2], t1[3]));
            w2.x = __builtin_bit_cast(unsigned, __builtin_amdgcn_cvt_pkrtz(t2[0], t2[1]));
            w2.y = __builtin_bit_cast(unsigned, __builtin_amdgcn_cvt_pkrtz(t2[2], t2[3]));
            *reinterpret_cast<uint2*>(&hbuf[bb][j0])      = w1;
            *reinterpret_cast<uint2*>(&hbuf[bb][16 + j0]) = w2;
        }

        cx0 = nx0; cx1 = nx1; cx2 = nx2;
    }

    // h_n = h_T @ W_fc^T + b_fc (single wave; h in hbuf)
    if (gq < 2) {
        const int o = gq;
        float acc = b_fc[o];
#pragma unroll
        for (int kk = 0; kk < 32; ++kk)
            acc = fmaf(W_fc[o * 32 + kk], (float)hbuf[bb][kk], acc);
        hn_out[(size_t)b * 2 + o] = acc;
    }
}

extern "C" void kernel_launch(void* const* d_in, const int* in_sizes, int n_in,
                              void* d_out, int out_size, void* d_ws, size_t ws_size,
                              hipStream_t stream) {
    const float* x    = (const float*)d_in[0];
    const float* W_ih = (const float*)d_in[1];
    const float* b_ih = (const float*)d_in[2];
    const float* W_hh = (const float*)d_in[3];
    const float* b_hh = (const float*)d_in[4];
    const float* W_fc = (const float*)d_in[5];
    const float* b_fc = (const float*)d_in[6];

    float* out    = (float*)d_out;                          // [B,T,H]
    float* hn_out = out + (size_t)RNN_B * RNN_T * 32;       // [B,2]

    const int grid = RNN_B / 16;   // 256 blocks x 1 wave (16 batches each)
    vanilla_rnn_kernel<<<grid, 64, 0, stream>>>(
        x, W_ih, b_ih, W_hh, b_hh, W_fc, b_fc, out, hn_out);
}